// Round 1
// baseline (443.759 us; speedup 1.0000x reference)
//
#include <hip/hip_runtime.h>
#include <hip/hip_bf16.h>

#define NROWS 8192
#define DIM 512
#define NCLASS 100
#define NQ 4            // class-sum quarters
#define NSLICE 8
#define INV_TEMP 14.285714285714286f
#define M0 14.285714285714286f
#define K2C 20.609929155556663f   // (1/T)*log2(e)

typedef __bf16 bf16x8 __attribute__((ext_vector_type(8)));
typedef float f32x4 __attribute__((ext_vector_type(4)));

// ws layout (bytes)
#define OFF_FB   0u            // 8192*512*2  = 8388608
#define OFF_SP   8388608u      // 8*8192*4    = 262144
#define OFF_G    8650752u      // 4*100*512*4 = 819200
#define OFF_CNT  9469952u      // 4*100*4     = 1600
#define OFF_RV   9471552u      // 8192*4      = 32768

__device__ __forceinline__ float bf2f(unsigned short u) {
    return __uint_as_float(((unsigned int)u) << 16);
}

// ---- 1. L2-normalize rows, emit bf16 ----
__global__ void norm_kernel(const float* __restrict__ F, unsigned short* __restrict__ Fb) {
    int row  = blockIdx.x * 4 + (threadIdx.x >> 6);
    int lane = threadIdx.x & 63;
    const float4* src = (const float4*)(F + (size_t)row * DIM);
    float4 a = src[lane];
    float4 b = src[lane + 64];
    float ss = a.x*a.x + a.y*a.y + a.z*a.z + a.w*a.w
             + b.x*b.x + b.y*b.y + b.z*b.z + b.w*b.w;
    #pragma unroll
    for (int off = 32; off; off >>= 1) ss += __shfl_xor(ss, off);
    float inv = 1.0f / sqrtf(ss);
    ushort4 oa, ob;
    oa.x = __builtin_bit_cast(unsigned short, (__bf16)(a.x * inv));
    oa.y = __builtin_bit_cast(unsigned short, (__bf16)(a.y * inv));
    oa.z = __builtin_bit_cast(unsigned short, (__bf16)(a.z * inv));
    oa.w = __builtin_bit_cast(unsigned short, (__bf16)(a.w * inv));
    ob.x = __builtin_bit_cast(unsigned short, (__bf16)(b.x * inv));
    ob.y = __builtin_bit_cast(unsigned short, (__bf16)(b.y * inv));
    ob.z = __builtin_bit_cast(unsigned short, (__bf16)(b.z * inv));
    ob.w = __builtin_bit_cast(unsigned short, (__bf16)(b.w * inv));
    ushort4* dst = (ushort4*)(Fb + (size_t)row * DIM);
    dst[lane]      = oa;
    dst[lane + 64] = ob;
}

// ---- 2. per-class feature sums + counts (quartered over rows) ----
__global__ void classsum_kernel(const unsigned short* __restrict__ Fb,
                                const int* __restrict__ labels,
                                float* __restrict__ G, float* __restrict__ cntp) {
    int c = blockIdx.x % NCLASS;
    int q = blockIdx.x / NCLASS;
    int r0 = q * (NROWS / NQ);
    __shared__ int slab[NROWS / NQ];
    for (int i = threadIdx.x; i < NROWS / NQ; i += 256) slab[i] = labels[r0 + i];
    __syncthreads();
    int d0 = threadIdx.x, d1 = threadIdx.x + 256;
    float g0 = 0.f, g1 = 0.f;
    int cnt = 0;
    for (int r = 0; r < NROWS / NQ; ++r) {
        if (slab[r] == c) {
            const unsigned short* row = Fb + (size_t)(r0 + r) * DIM;
            g0 += bf2f(row[d0]);
            g1 += bf2f(row[d1]);
            cnt++;
        }
    }
    float* grow = G + ((size_t)q * NCLASS + c) * DIM;
    grow[d0] = g0;
    grow[d1] = g1;
    if (threadIdx.x == 0) cntp[q * NCLASS + c] = (float)cnt;
}

// ---- 3. MFMA similarity + exp-sum (denominator) ----
__global__ __launch_bounds__(256, 2)
void simstats_kernel(const unsigned short* __restrict__ Fb, float* __restrict__ Sp) {
    int strip = blockIdx.x >> 1;                 // 0..255 (32 rows each)
    int w     = threadIdx.x >> 6;
    int slice = ((blockIdx.x & 1) << 2) | w;     // 0..7 (1024 cols each)
    int lane  = threadIdx.x & 63;
    int col   = lane & 15;
    int kg    = lane >> 4;                        // 0..3
    int r0    = strip * 32;

    // A fragments: 2 m-tiles x 16 k-steps, pinned in registers
    bf16x8 afr[2][16];
    #pragma unroll
    for (int m = 0; m < 2; ++m) {
        const unsigned short* arow = Fb + (size_t)(r0 + m * 16 + col) * DIM + kg * 8;
        #pragma unroll
        for (int kk = 0; kk < 16; ++kk)
            afr[m][kk] = __builtin_bit_cast(bf16x8, *(const uint4*)(arow + kk * 32));
    }

    float S[2][4] = {{0.f,0.f,0.f,0.f},{0.f,0.f,0.f,0.f}};
    int jb0 = slice * (NROWS / NSLICE);

    for (int jt = 0; jt < (NROWS / NSLICE) / 16; ++jt) {
        const unsigned short* brow = Fb + (size_t)(jb0 + jt * 16 + col) * DIM + kg * 8;
        f32x4 acc0 = {0.f,0.f,0.f,0.f}, acc1 = {0.f,0.f,0.f,0.f};
        #pragma unroll
        for (int kk = 0; kk < 16; ++kk) {
            bf16x8 bfr = __builtin_bit_cast(bf16x8, *(const uint4*)(brow + kk * 32));
            acc0 = __builtin_amdgcn_mfma_f32_16x16x32_bf16(afr[0][kk], bfr, acc0, 0, 0, 0);
            acc1 = __builtin_amdgcn_mfma_f32_16x16x32_bf16(afr[1][kk], bfr, acc1, 0, 0, 0);
        }
        #pragma unroll
        for (int r = 0; r < 4; ++r) {
            S[0][r] += exp2f(fmaf(acc0[r], K2C, -K2C));
            S[1][r] += exp2f(fmaf(acc1[r], K2C, -K2C));
        }
    }

    // reduce over the 16 lanes of each row-group (cols mod 16)
    #pragma unroll
    for (int off = 1; off < 16; off <<= 1) {
        #pragma unroll
        for (int m = 0; m < 2; ++m)
            #pragma unroll
            for (int r = 0; r < 4; ++r)
                S[m][r] += __shfl_xor(S[m][r], off);
    }
    if (col == 0) {
        #pragma unroll
        for (int m = 0; m < 2; ++m)
            #pragma unroll
            for (int r = 0; r < 4; ++r)
                Sp[(size_t)slice * NROWS + r0 + m * 16 + kg * 4 + r] = S[m][r];
    }
}

// ---- 4. per-row loss term ----
__global__ void finalize_kernel(const unsigned short* __restrict__ Fb,
                                const int* __restrict__ labels,
                                const float* __restrict__ Sp,
                                const float* __restrict__ G,
                                const float* __restrict__ cntp,
                                float* __restrict__ rowvals) {
    int i = blockIdx.x * 256 + threadIdx.x;
    int lab = labels[i];
    const unsigned short* row = Fb + (size_t)i * DIM;
    const float* g0 = G + ((size_t)0 * NCLASS + lab) * DIM;
    const float* g1 = G + ((size_t)1 * NCLASS + lab) * DIM;
    const float* g2 = G + ((size_t)2 * NCLASS + lab) * DIM;
    const float* g3 = G + ((size_t)3 * NCLASS + lab) * DIM;
    float ss = 0.f, dot = 0.f;
    #pragma unroll 4
    for (int k = 0; k < DIM; ++k) {
        float f = bf2f(row[k]);
        float g = g0[k] + g1[k] + g2[k] + g3[k];
        ss  = fmaf(f, f, ss);
        dot = fmaf(f, g, dot);
    }
    float cnt = cntp[lab] + cntp[NCLASS + lab] + cntp[2 * NCLASS + lab] + cntp[3 * NCLASS + lab];
    float S0 = 0.f;
    #pragma unroll
    for (int s = 0; s < NSLICE; ++s) S0 += Sp[(size_t)s * NROWS + i];
    float eself = exp2f(fmaf(ss, K2C, -K2C));
    float S = S0 - eself + 1e-12f;
    // -(mean_log_prob_pos) = M0 + log(S) - P/cnt
    rowvals[i] = M0 + logf(S) - (dot * INV_TEMP) / cnt;
}

// ---- 5. scalar reduce ----
__global__ void reduce_kernel(const float* __restrict__ rowvals, float* __restrict__ out) {
    float s = 0.f;
    for (int i = threadIdx.x; i < NROWS; i += 256) s += rowvals[i];
    #pragma unroll
    for (int off = 32; off; off >>= 1) s += __shfl_xor(s, off);
    __shared__ float buf[4];
    int w = threadIdx.x >> 6;
    if ((threadIdx.x & 63) == 0) buf[w] = s;
    __syncthreads();
    if (threadIdx.x == 0) out[0] = (buf[0] + buf[1] + buf[2] + buf[3]) * (1.0f / (float)NROWS);
}

extern "C" void kernel_launch(void* const* d_in, const int* in_sizes, int n_in,
                              void* d_out, int out_size, void* d_ws, size_t ws_size,
                              hipStream_t stream) {
    const float* F      = (const float*)d_in[0];
    const int*   labels = (const int*)d_in[1];
    float*       out    = (float*)d_out;
    char*        ws     = (char*)d_ws;

    unsigned short* Fb   = (unsigned short*)(ws + OFF_FB);
    float*          Sp   = (float*)(ws + OFF_SP);
    float*          G    = (float*)(ws + OFF_G);
    float*          cntp = (float*)(ws + OFF_CNT);
    float*          rv   = (float*)(ws + OFF_RV);

    norm_kernel<<<NROWS / 4, 256, 0, stream>>>(F, Fb);
    classsum_kernel<<<NCLASS * NQ, 256, 0, stream>>>(Fb, labels, G, cntp);
    simstats_kernel<<<512, 256, 0, stream>>>(Fb, Sp);
    finalize_kernel<<<NROWS / 256, 256, 0, stream>>>(Fb, labels, Sp, G, cntp, rv);
    reduce_kernel<<<1, 256, 0, stream>>>(rv, out);
}

// Round 2
// 199.607 us; speedup vs baseline: 2.2232x; 2.2232x over previous
//
#include <hip/hip_runtime.h>
#include <hip/hip_bf16.h>

#define NROWS 8192
#define DIM 512
#define NCLASS 100
#define NQ 4            // class-sum quarters
#define NSLICE 8
#define NT 16           // 64-col tiles per 1024-col slice
#define INV_TEMP 14.285714285714286f
#define M0 14.285714285714286f
#define K2C 20.609929155556663f   // (1/T)*log2(e)

typedef __bf16 bf16x8 __attribute__((ext_vector_type(8)));
typedef float f32x4 __attribute__((ext_vector_type(4)));

// ws layout (bytes)
#define OFF_FB   0u            // 8192*512*2  = 8388608
#define OFF_SP   8388608u      // 8*8192*4    = 262144
#define OFF_G    8650752u      // 4*100*512*4 = 819200
#define OFF_CNT  9469952u      // 4*100*4     = 1600
#define OFF_GC   9471552u      // 100*512*4   = 204800
#define OFF_CC   9676352u      // 100*4       = 400
#define OFF_RV   9676800u      // 8192*4      = 32768

#define AS1(p) ((const __attribute__((address_space(1))) void*)(p))
#define AS3(p) ((__attribute__((address_space(3))) void*)(p))

__device__ __forceinline__ float bf2f(unsigned short u) {
    return __uint_as_float(((unsigned int)u) << 16);
}

// ---- 1. L2-normalize rows, emit bf16 ----
__global__ void norm_kernel(const float* __restrict__ F, unsigned short* __restrict__ Fb) {
    int row  = blockIdx.x * 4 + (threadIdx.x >> 6);
    int lane = threadIdx.x & 63;
    const float4* src = (const float4*)(F + (size_t)row * DIM);
    float4 a = src[lane];
    float4 b = src[lane + 64];
    float ss = a.x*a.x + a.y*a.y + a.z*a.z + a.w*a.w
             + b.x*b.x + b.y*b.y + b.z*b.z + b.w*b.w;
    #pragma unroll
    for (int off = 32; off; off >>= 1) ss += __shfl_xor(ss, off);
    float inv = 1.0f / sqrtf(ss);
    ushort4 oa, ob;
    oa.x = __builtin_bit_cast(unsigned short, (__bf16)(a.x * inv));
    oa.y = __builtin_bit_cast(unsigned short, (__bf16)(a.y * inv));
    oa.z = __builtin_bit_cast(unsigned short, (__bf16)(a.z * inv));
    oa.w = __builtin_bit_cast(unsigned short, (__bf16)(a.w * inv));
    ob.x = __builtin_bit_cast(unsigned short, (__bf16)(b.x * inv));
    ob.y = __builtin_bit_cast(unsigned short, (__bf16)(b.y * inv));
    ob.z = __builtin_bit_cast(unsigned short, (__bf16)(b.z * inv));
    ob.w = __builtin_bit_cast(unsigned short, (__bf16)(b.w * inv));
    ushort4* dst = (ushort4*)(Fb + (size_t)row * DIM);
    dst[lane]      = oa;
    dst[lane + 64] = ob;
}

// ---- 2. per-class feature sums + counts (quartered over rows) ----
__global__ void classsum_kernel(const unsigned short* __restrict__ Fb,
                                const int* __restrict__ labels,
                                float* __restrict__ G, float* __restrict__ cntp) {
    int c = blockIdx.x % NCLASS;
    int q = blockIdx.x / NCLASS;
    int r0 = q * (NROWS / NQ);
    __shared__ int slab[NROWS / NQ];
    for (int i = threadIdx.x; i < NROWS / NQ; i += 256) slab[i] = labels[r0 + i];
    __syncthreads();
    int d0 = threadIdx.x, d1 = threadIdx.x + 256;
    float g0 = 0.f, g1 = 0.f;
    int cnt = 0;
    for (int r = 0; r < NROWS / NQ; ++r) {
        if (slab[r] == c) {
            const unsigned short* row = Fb + (size_t)(r0 + r) * DIM;
            g0 += bf2f(row[d0]);
            g1 += bf2f(row[d1]);
            cnt++;
        }
    }
    float* grow = G + ((size_t)q * NCLASS + c) * DIM;
    grow[d0] = g0;
    grow[d1] = g1;
    if (threadIdx.x == 0) cntp[q * NCLASS + c] = (float)cnt;
}

// ---- 2b. combine quarters ----
__global__ void combine_kernel(const float* __restrict__ G, const float* __restrict__ cntp,
                               float* __restrict__ Gc, float* __restrict__ cntc) {
    int idx = blockIdx.x * 256 + threadIdx.x;   // 0..51199
    const int Q = NCLASS * DIM;
    Gc[idx] = G[idx] + G[Q + idx] + G[2 * Q + idx] + G[3 * Q + idx];
    if (idx < NCLASS)
        cntc[idx] = cntp[idx] + cntp[NCLASS + idx] + cntp[2 * NCLASS + idx] + cntp[3 * NCLASS + idx];
}

// ---- 3. MFMA similarity + exp-sum, LDS-staged B, double-buffered ----
__global__ __launch_bounds__(512, 2)
void simstats_kernel(const unsigned short* __restrict__ Fb, float* __restrict__ Sp) {
    __shared__ unsigned short lds[2][64][512];   // 128 KiB
    int strip = blockIdx.x >> 3;                 // 0..31  (256 rows)
    int slice = blockIdx.x & 7;                  // 0..7   (1024 cols)
    int w     = threadIdx.x >> 6;                // 0..7
    int lane  = threadIdx.x & 63;
    int col   = lane & 15;
    int kg    = lane >> 4;                       // 0..3
    int r0    = strip * 256 + w * 32;
    int jb0   = slice * 1024;

    // A fragments pinned: 2 m-tiles x 16 k-steps (128 VGPR)
    bf16x8 afr[2][16];
    #pragma unroll
    for (int m = 0; m < 2; ++m) {
        const unsigned short* arow = Fb + (size_t)(r0 + m * 16 + col) * DIM + kg * 8;
        #pragma unroll
        for (int kk = 0; kk < 16; ++kk)
            afr[m][kk] = __builtin_bit_cast(bf16x8, *(const uint4*)(arow + kk * 32));
    }

    // stage 64-col tile t into lds[b]; LDS linear, global source pre-swizzled
    // (read side applies byte ^= ((row&7)<<4); one wave-issue fills one row)
    auto stage = [&](int b, int t) {
        #pragma unroll
        for (int i = 0; i < 8; ++i) {
            int n = i * 8 + w;                               // wave-uniform row
            const unsigned short* src =
                Fb + (size_t)(jb0 + t * 64 + n) * DIM + ((lane ^ (n & 7)) << 3);
            __builtin_amdgcn_global_load_lds(AS1(src), AS3(&lds[b][n][0]), 16, 0, 0);
        }
    };

    float S[2][4] = {{0.f,0.f,0.f,0.f},{0.f,0.f,0.f,0.f}};
    int kbase = ((kg ^ (col & 7)) << 4);

    auto compute = [&](int b) {
        #pragma unroll
        for (int ct = 0; ct < 4; ++ct) {
            const char* rowbase = (const char*)&lds[b][ct * 16 + col][0];
            f32x4 acc0 = {0.f,0.f,0.f,0.f}, acc1 = {0.f,0.f,0.f,0.f};
            #pragma unroll
            for (int kk = 0; kk < 16; ++kk) {
                bf16x8 bfr = __builtin_bit_cast(bf16x8,
                    *(const uint4*)(rowbase + ((kk << 6) ^ kbase)));
                acc0 = __builtin_amdgcn_mfma_f32_16x16x32_bf16(afr[0][kk], bfr, acc0, 0, 0, 0);
                acc1 = __builtin_amdgcn_mfma_f32_16x16x32_bf16(afr[1][kk], bfr, acc1, 0, 0, 0);
            }
            #pragma unroll
            for (int r = 0; r < 4; ++r) {
                S[0][r] += exp2f(fmaf(acc0[r], K2C, -K2C));
                S[1][r] += exp2f(fmaf(acc1[r], K2C, -K2C));
            }
        }
    };

    stage(0, 0);
    for (int t = 0; t < NT; ++t) {
        __syncthreads();                       // tile t staged; prev reads drained
        if (t + 1 < NT) stage((t + 1) & 1, t + 1);
        compute(t & 1);
    }

    // sum across the 16 lanes holding the same output rows
    #pragma unroll
    for (int off = 1; off < 16; off <<= 1) {
        #pragma unroll
        for (int m = 0; m < 2; ++m)
            #pragma unroll
            for (int r = 0; r < 4; ++r)
                S[m][r] += __shfl_xor(S[m][r], off);
    }
    if (col == 0) {
        #pragma unroll
        for (int m = 0; m < 2; ++m)
            #pragma unroll
            for (int r = 0; r < 4; ++r)
                Sp[(size_t)slice * NROWS + r0 + m * 16 + kg * 4 + r] = S[m][r];
    }
}

// ---- 4. per-row loss term: one wave per row ----
__global__ void finalize_kernel(const unsigned short* __restrict__ Fb,
                                const int* __restrict__ labels,
                                const float* __restrict__ Sp,
                                const float* __restrict__ Gc,
                                const float* __restrict__ cntc,
                                float* __restrict__ rowvals) {
    int i    = blockIdx.x * 4 + (threadIdx.x >> 6);
    int lane = threadIdx.x & 63;
    int lab  = labels[i];
    uint4 rv = *(const uint4*)(Fb + (size_t)i * DIM + lane * 8);
    const float4* gp = (const float4*)(Gc + (size_t)lab * DIM + lane * 8);
    float4 ga = gp[0], gb = gp[1];
    float f0 = __uint_as_float(rv.x << 16), f1 = __uint_as_float(rv.x & 0xffff0000u);
    float f2 = __uint_as_float(rv.y << 16), f3 = __uint_as_float(rv.y & 0xffff0000u);
    float f4 = __uint_as_float(rv.z << 16), f5 = __uint_as_float(rv.z & 0xffff0000u);
    float f6 = __uint_as_float(rv.w << 16), f7 = __uint_as_float(rv.w & 0xffff0000u);
    float ss  = f0*f0 + f1*f1 + f2*f2 + f3*f3 + f4*f4 + f5*f5 + f6*f6 + f7*f7;
    float dot = f0*ga.x + f1*ga.y + f2*ga.z + f3*ga.w
              + f4*gb.x + f5*gb.y + f6*gb.z + f7*gb.w;
    float sadd = (lane < NSLICE) ? Sp[(size_t)lane * NROWS + i] : 0.f;
    #pragma unroll
    for (int off = 32; off; off >>= 1) {
        ss   += __shfl_xor(ss, off);
        dot  += __shfl_xor(dot, off);
        sadd += __shfl_xor(sadd, off);
    }
    if (lane == 0) {
        float cnt   = cntc[lab];
        float eself = exp2f(fmaf(ss, K2C, -K2C));
        float S     = sadd - eself + 1e-12f;
        rowvals[i]  = M0 + logf(S) - (dot * INV_TEMP) / cnt;
    }
}

// ---- 5. scalar reduce ----
__global__ void reduce_kernel(const float* __restrict__ rowvals, float* __restrict__ out) {
    float s = 0.f;
    for (int i = threadIdx.x; i < NROWS; i += 256) s += rowvals[i];
    #pragma unroll
    for (int off = 32; off; off >>= 1) s += __shfl_xor(s, off);
    __shared__ float buf[4];
    int w = threadIdx.x >> 6;
    if ((threadIdx.x & 63) == 0) buf[w] = s;
    __syncthreads();
    if (threadIdx.x == 0) out[0] = (buf[0] + buf[1] + buf[2] + buf[3]) * (1.0f / (float)NROWS);
}

extern "C" void kernel_launch(void* const* d_in, const int* in_sizes, int n_in,
                              void* d_out, int out_size, void* d_ws, size_t ws_size,
                              hipStream_t stream) {
    const float* F      = (const float*)d_in[0];
    const int*   labels = (const int*)d_in[1];
    float*       out    = (float*)d_out;
    char*        ws     = (char*)d_ws;

    unsigned short* Fb   = (unsigned short*)(ws + OFF_FB);
    float*          Sp   = (float*)(ws + OFF_SP);
    float*          G    = (float*)(ws + OFF_G);
    float*          cntp = (float*)(ws + OFF_CNT);
    float*          Gc   = (float*)(ws + OFF_GC);
    float*          cc   = (float*)(ws + OFF_CC);
    float*          rv   = (float*)(ws + OFF_RV);

    norm_kernel<<<NROWS / 4, 256, 0, stream>>>(F, Fb);
    classsum_kernel<<<NCLASS * NQ, 256, 0, stream>>>(Fb, labels, G, cntp);
    combine_kernel<<<(NCLASS * DIM) / 256, 256, 0, stream>>>(G, cntp, Gc, cc);
    simstats_kernel<<<256, 512, 0, stream>>>(Fb, Sp);
    finalize_kernel<<<NROWS / 4, 256, 0, stream>>>(Fb, labels, Sp, Gc, cc, rv);
    reduce_kernel<<<1, 256, 0, stream>>>(rv, out);
}

// Round 3
// 124.644 us; speedup vs baseline: 3.5602x; 1.6014x over previous
//
#include <hip/hip_runtime.h>
#include <hip/hip_bf16.h>

#define NROWS 8192
#define DIM 512
#define NCLASS 100
#define NQ 4            // class-sum quarters
#define NSLICE 8
#define NT 16           // 64-col tiles per 1024-col slice
#define LISTCAP 1024
#define INV_TEMP 14.285714285714286f
#define M0 14.285714285714286f
#define K2C 20.609929155556663f   // (1/T)*log2(e)

typedef __bf16 bf16x8 __attribute__((ext_vector_type(8)));
typedef float f32x4 __attribute__((ext_vector_type(4)));

// ws layout (bytes)
#define OFF_FB   0u            // 8192*512*2  = 8388608
#define OFF_SP   8388608u      // 8*8192*4    = 262144
#define OFF_G    8650752u      // 4*100*512*4 = 819200
#define OFF_GC   9471552u      // 100*512*4   = 204800
#define OFF_CC   9676352u      // 100*4       = 400
#define OFF_RV   9676800u      // 8192*4      = 32768
#define OFF_LIST 9709568u      // 100*1024*4  = 409600
#define OFF_ICNT 10119168u     // 100*4       = 400

#define AS1(p) ((const __attribute__((address_space(1))) void*)(p))
#define AS3(p) ((__attribute__((address_space(3))) void*)(p))

__device__ __forceinline__ float bf2f(unsigned short u) {
    return __uint_as_float(((unsigned int)u) << 16);
}

// ---- 1. L2-normalize rows -> bf16; build per-class row lists ----
__global__ void norm_kernel(const float* __restrict__ F, const int* __restrict__ labels,
                            unsigned short* __restrict__ Fb,
                            int* __restrict__ cnt, int* __restrict__ lists) {
    int row  = blockIdx.x * 4 + (threadIdx.x >> 6);
    int lane = threadIdx.x & 63;
    const float4* src = (const float4*)(F + (size_t)row * DIM);
    float4 a = src[lane];
    float4 b = src[lane + 64];
    float ss = a.x*a.x + a.y*a.y + a.z*a.z + a.w*a.w
             + b.x*b.x + b.y*b.y + b.z*b.z + b.w*b.w;
    #pragma unroll
    for (int off = 32; off; off >>= 1) ss += __shfl_xor(ss, off);
    float inv = 1.0f / sqrtf(ss);
    ushort4 oa, ob;
    oa.x = __builtin_bit_cast(unsigned short, (__bf16)(a.x * inv));
    oa.y = __builtin_bit_cast(unsigned short, (__bf16)(a.y * inv));
    oa.z = __builtin_bit_cast(unsigned short, (__bf16)(a.z * inv));
    oa.w = __builtin_bit_cast(unsigned short, (__bf16)(a.w * inv));
    ob.x = __builtin_bit_cast(unsigned short, (__bf16)(b.x * inv));
    ob.y = __builtin_bit_cast(unsigned short, (__bf16)(b.y * inv));
    ob.z = __builtin_bit_cast(unsigned short, (__bf16)(b.z * inv));
    ob.w = __builtin_bit_cast(unsigned short, (__bf16)(b.w * inv));
    ushort4* dst = (ushort4*)(Fb + (size_t)row * DIM);
    dst[lane]      = oa;
    dst[lane + 64] = ob;
    if (lane == 0) {
        int lab = labels[row];
        int pos = atomicAdd(&cnt[lab], 1);
        if (pos < LISTCAP) lists[lab * LISTCAP + pos] = row;
    }
}

// ---- 2. per-class feature sums via row lists (quartered) ----
__global__ void classsum_kernel(const unsigned short* __restrict__ Fb,
                                const int* __restrict__ cnt,
                                const int* __restrict__ lists,
                                float* __restrict__ G) {
    int c = blockIdx.x % NCLASS;
    int q = blockIdx.x / NCLASS;
    int n = cnt[c];
    int lo = (n * q) / NQ, hi = (n * (q + 1)) / NQ;
    const int* lst = lists + c * LISTCAP;
    float g0 = 0.f, g1 = 0.f;
    #pragma unroll 4
    for (int p = lo; p < hi; ++p) {
        int r = lst[p];
        unsigned int u = *(const unsigned int*)(Fb + (size_t)r * DIM + threadIdx.x * 2);
        g0 += __uint_as_float(u << 16);
        g1 += __uint_as_float(u & 0xffff0000u);
    }
    float2* grow = (float2*)(G + ((size_t)q * NCLASS + c) * DIM);
    grow[threadIdx.x] = make_float2(g0, g1);
}

// ---- 2b. combine quarters ----
__global__ void combine_kernel(const float* __restrict__ G, const int* __restrict__ cnt,
                               float* __restrict__ Gc, float* __restrict__ cntc) {
    int idx = blockIdx.x * 256 + threadIdx.x;   // 0..51199
    const int Q = NCLASS * DIM;
    Gc[idx] = G[idx] + G[Q + idx] + G[2 * Q + idx] + G[3 * Q + idx];
    if (idx < NCLASS) cntc[idx] = (float)cnt[idx];
}

// ---- 3. MFMA similarity + exp-sum, LDS-staged B, double-buffered ----
__global__ __launch_bounds__(512, 2)
void simstats_kernel(const unsigned short* __restrict__ Fb, float* __restrict__ Sp) {
    __shared__ unsigned short lds[2][64][512];   // 128 KiB
    int strip = blockIdx.x >> 3;                 // 0..31  (256 rows)
    int slice = blockIdx.x & 7;                  // 0..7   (1024 cols)
    int w     = threadIdx.x >> 6;                // 0..7
    int lane  = threadIdx.x & 63;
    int col   = lane & 15;
    int kg    = lane >> 4;                       // 0..3
    int r0    = strip * 256 + w * 32;
    int jb0   = slice * 1024;

    // A fragments pinned: 2 m-tiles x 16 k-steps (128 VGPR)
    bf16x8 afr[2][16];
    #pragma unroll
    for (int m = 0; m < 2; ++m) {
        const unsigned short* arow = Fb + (size_t)(r0 + m * 16 + col) * DIM + kg * 8;
        #pragma unroll
        for (int kk = 0; kk < 16; ++kk)
            afr[m][kk] = __builtin_bit_cast(bf16x8, *(const uint4*)(arow + kk * 32));
    }

    // stage 64-col tile t into lds[b]; LDS linear, global source pre-swizzled
    auto stage = [&](int b, int t) {
        #pragma unroll
        for (int i = 0; i < 8; ++i) {
            int n = i * 8 + w;                               // wave-uniform row
            const unsigned short* src =
                Fb + (size_t)(jb0 + t * 64 + n) * DIM + ((lane ^ (n & 7)) << 3);
            __builtin_amdgcn_global_load_lds(AS1(src), AS3(&lds[b][n][0]), 16, 0, 0);
        }
    };

    float S[2][4] = {{0.f,0.f,0.f,0.f},{0.f,0.f,0.f,0.f}};
    int kbase = ((kg ^ (col & 7)) << 4);

    auto compute = [&](int b) {
        #pragma unroll
        for (int ct = 0; ct < 4; ++ct) {
            const char* rowbase = (const char*)&lds[b][ct * 16 + col][0];
            f32x4 acc0 = {0.f,0.f,0.f,0.f}, acc1 = {0.f,0.f,0.f,0.f};
            #pragma unroll
            for (int kk = 0; kk < 16; ++kk) {
                bf16x8 bfr = __builtin_bit_cast(bf16x8,
                    *(const uint4*)(rowbase + ((kk << 6) ^ kbase)));
                acc0 = __builtin_amdgcn_mfma_f32_16x16x32_bf16(afr[0][kk], bfr, acc0, 0, 0, 0);
                acc1 = __builtin_amdgcn_mfma_f32_16x16x32_bf16(afr[1][kk], bfr, acc1, 0, 0, 0);
            }
            #pragma unroll
            for (int r = 0; r < 4; ++r) {
                S[0][r] += exp2f(fmaf(acc0[r], K2C, -K2C));
                S[1][r] += exp2f(fmaf(acc1[r], K2C, -K2C));
            }
        }
    };

    stage(0, 0);
    for (int t = 0; t < NT; ++t) {
        __syncthreads();                       // tile t staged; prev reads drained
        if (t + 1 < NT) stage((t + 1) & 1, t + 1);
        compute(t & 1);
    }

    // sum across the 16 lanes holding the same output rows
    #pragma unroll
    for (int off = 1; off < 16; off <<= 1) {
        #pragma unroll
        for (int m = 0; m < 2; ++m)
            #pragma unroll
            for (int r = 0; r < 4; ++r)
                S[m][r] += __shfl_xor(S[m][r], off);
    }
    if (col == 0) {
        #pragma unroll
        for (int m = 0; m < 2; ++m)
            #pragma unroll
            for (int r = 0; r < 4; ++r)
                Sp[(size_t)slice * NROWS + r0 + m * 16 + kg * 4 + r] = S[m][r];
    }
}

// ---- 4. per-row loss term: one wave per row ----
__global__ void finalize_kernel(const unsigned short* __restrict__ Fb,
                                const int* __restrict__ labels,
                                const float* __restrict__ Sp,
                                const float* __restrict__ Gc,
                                const float* __restrict__ cntc,
                                float* __restrict__ rowvals) {
    int i    = blockIdx.x * 4 + (threadIdx.x >> 6);
    int lane = threadIdx.x & 63;
    int lab  = labels[i];
    uint4 rv = *(const uint4*)(Fb + (size_t)i * DIM + lane * 8);
    const float4* gp = (const float4*)(Gc + (size_t)lab * DIM + lane * 8);
    float4 ga = gp[0], gb = gp[1];
    float f0 = __uint_as_float(rv.x << 16), f1 = __uint_as_float(rv.x & 0xffff0000u);
    float f2 = __uint_as_float(rv.y << 16), f3 = __uint_as_float(rv.y & 0xffff0000u);
    float f4 = __uint_as_float(rv.z << 16), f5 = __uint_as_float(rv.z & 0xffff0000u);
    float f6 = __uint_as_float(rv.w << 16), f7 = __uint_as_float(rv.w & 0xffff0000u);
    float ss  = f0*f0 + f1*f1 + f2*f2 + f3*f3 + f4*f4 + f5*f5 + f6*f6 + f7*f7;
    float dot = f0*ga.x + f1*ga.y + f2*ga.z + f3*ga.w
              + f4*gb.x + f5*gb.y + f6*gb.z + f7*gb.w;
    float sadd = (lane < NSLICE) ? Sp[(size_t)lane * NROWS + i] : 0.f;
    #pragma unroll
    for (int off = 32; off; off >>= 1) {
        ss   += __shfl_xor(ss, off);
        dot  += __shfl_xor(dot, off);
        sadd += __shfl_xor(sadd, off);
    }
    if (lane == 0) {
        float cnt   = cntc[lab];
        float eself = exp2f(fmaf(ss, K2C, -K2C));
        float S     = sadd - eself + 1e-12f;
        rowvals[i]  = M0 + logf(S) - (dot * INV_TEMP) / cnt;
    }
}

// ---- 5. scalar reduce ----
__global__ void reduce_kernel(const float* __restrict__ rowvals, float* __restrict__ out) {
    float s = 0.f;
    for (int i = threadIdx.x; i < NROWS; i += 256) s += rowvals[i];
    #pragma unroll
    for (int off = 32; off; off >>= 1) s += __shfl_xor(s, off);
    __shared__ float buf[4];
    int w = threadIdx.x >> 6;
    if ((threadIdx.x & 63) == 0) buf[w] = s;
    __syncthreads();
    if (threadIdx.x == 0) out[0] = (buf[0] + buf[1] + buf[2] + buf[3]) * (1.0f / (float)NROWS);
}

extern "C" void kernel_launch(void* const* d_in, const int* in_sizes, int n_in,
                              void* d_out, int out_size, void* d_ws, size_t ws_size,
                              hipStream_t stream) {
    const float* F      = (const float*)d_in[0];
    const int*   labels = (const int*)d_in[1];
    float*       out    = (float*)d_out;
    char*        ws     = (char*)d_ws;

    unsigned short* Fb    = (unsigned short*)(ws + OFF_FB);
    float*          Sp    = (float*)(ws + OFF_SP);
    float*          G     = (float*)(ws + OFF_G);
    float*          Gc    = (float*)(ws + OFF_GC);
    float*          cc    = (float*)(ws + OFF_CC);
    float*          rv    = (float*)(ws + OFF_RV);
    int*            lists = (int*)(ws + OFF_LIST);
    int*            icnt  = (int*)(ws + OFF_ICNT);

    hipMemsetAsync(icnt, 0, NCLASS * sizeof(int), stream);
    norm_kernel<<<NROWS / 4, 256, 0, stream>>>(F, labels, Fb, icnt, lists);
    classsum_kernel<<<NCLASS * NQ, 256, 0, stream>>>(Fb, icnt, lists, G);
    combine_kernel<<<(NCLASS * DIM) / 256, 256, 0, stream>>>(G, icnt, Gc, cc);
    simstats_kernel<<<256, 512, 0, stream>>>(Fb, Sp);
    finalize_kernel<<<NROWS / 4, 256, 0, stream>>>(Fb, labels, Sp, Gc, cc, rv);
    reduce_kernel<<<1, 256, 0, stream>>>(rv, out);
}

// Round 4
// 108.570 us; speedup vs baseline: 4.0873x; 1.1480x over previous
//
#include <hip/hip_runtime.h>
#include <hip/hip_bf16.h>

#define NROWS 8192
#define DIM 512
#define NCLASS 100
#define NQ 2            // class-sum halves
#define NSLICE 16       // column slices of 512
#define NT 8            // 64-col tiles per slice
#define LISTCAP 1024
#define INV_TEMP 14.285714285714286f
#define M0 14.285714285714286f
#define K2C 20.609929155556663f   // (1/T)*log2(e)

typedef float f32x4 __attribute__((ext_vector_type(4)));
typedef long  i64x2 __attribute__((ext_vector_type(2)));

// ws layout (bytes)
#define OFF_FB   0u            // 8192*512*1  = 4194304 (fp8, fragment-paired layout)
#define OFF_SP   4194304u      // 16*8192*4   = 524288
#define OFF_G    4718592u      // 2*100*512*4 = 409600
#define OFF_LIST 5128192u      // 100*1024*4  = 409600
#define OFF_ICNT 5537792u      // 100*4
#define OFF_RV   5538192u      // 8192*4

#define AS1(p) ((const __attribute__((address_space(1))) void*)(p))
#define AS3(p) ((__attribute__((address_space(3))) void*)(p))

// Row byte layout (per 512-elem row): element e (k-index) with kk=e>>5 (MFMA K-step),
// kg=(e>>3)&3 (lane k-group), r=e&7 lives at byte  (kk>>1)*64 + kg*16 + (kk&1)*8 + r.
// => a 16B chunk at p*64+kg*16 holds the (kk=2p, kg) frag || (kk=2p+1, kg) frag.
// Same permutation for every row => all elementwise ops (class sums, dots) unaffected.

// ---- 1. L2-normalize rows -> fp8 (permuted layout); build per-class row lists ----
__global__ void norm_kernel(const float* __restrict__ F, const int* __restrict__ labels,
                            unsigned char* __restrict__ Fb,
                            int* __restrict__ cnt, int* __restrict__ lists) {
    int row  = blockIdx.x * 4 + (threadIdx.x >> 6);
    int lane = threadIdx.x & 63;
    const float4* src = (const float4*)(F + (size_t)row * DIM);
    float4 a = src[lane * 2];
    float4 b = src[lane * 2 + 1];
    float ss = a.x*a.x + a.y*a.y + a.z*a.z + a.w*a.w
             + b.x*b.x + b.y*b.y + b.z*b.z + b.w*b.w;
    #pragma unroll
    for (int off = 32; off; off >>= 1) ss += __shfl_xor(ss, off);
    float inv = 1.0f / sqrtf(ss);
    float f0 = a.x*inv, f1 = a.y*inv, f2 = a.z*inv, f3 = a.w*inv;
    float f4 = b.x*inv, f5 = b.y*inv, f6 = b.z*inv, f7 = b.w*inv;
    int w0 = __builtin_amdgcn_cvt_pk_fp8_f32(f0, f1, 0, false);
    w0     = __builtin_amdgcn_cvt_pk_fp8_f32(f2, f3, w0, true);
    int w1 = __builtin_amdgcn_cvt_pk_fp8_f32(f4, f5, 0, false);
    w1     = __builtin_amdgcn_cvt_pk_fp8_f32(f6, f7, w1, true);
    // this lane holds elements e = lane*8..lane*8+7 -> one (kk,kg) frag; kk=lane>>2, kg=lane&3
    int pofs = ((lane >> 3) << 6) + ((lane & 3) << 4) + (((lane >> 2) & 1) << 3);
    uint2 wv; wv.x = (unsigned)w0; wv.y = (unsigned)w1;
    *(uint2*)(Fb + (size_t)row * DIM + pofs) = wv;
    if (lane == 0) {
        int lab = labels[row];
        int pos = atomicAdd(&cnt[lab], 1);
        if (pos < LISTCAP) lists[lab * LISTCAP + pos] = row;
    }
}

// ---- 2. per-class feature sums via row lists (halved) ----
__global__ void classsum_kernel(const unsigned char* __restrict__ Fb,
                                const int* __restrict__ cnt,
                                const int* __restrict__ lists,
                                float* __restrict__ G) {
    int c = blockIdx.x % NCLASS;
    int q = blockIdx.x / NCLASS;
    int n = cnt[c];
    int lo = (n * q) / NQ, hi = (n * (q + 1)) / NQ;
    const int* lst = lists + c * LISTCAP;
    float g0 = 0.f, g1 = 0.f;
    #pragma unroll 4
    for (int p = lo; p < hi; ++p) {
        int r = lst[p];
        unsigned int u = *(const unsigned short*)(Fb + (size_t)r * DIM + threadIdx.x * 2);
        g0 += __builtin_amdgcn_cvt_f32_fp8(u, 0);
        g1 += __builtin_amdgcn_cvt_f32_fp8(u, 1);
    }
    float2* grow = (float2*)(G + ((size_t)q * NCLASS + c) * DIM);
    grow[threadIdx.x] = make_float2(g0, g1);
}

// ---- 3. FP8 MFMA similarity + exp-sum; paired-frag b128 LDS reads, chunk-XOR swizzle ----
__global__ __launch_bounds__(512, 4)
void simstats_kernel(const unsigned char* __restrict__ Fb, float* __restrict__ Sp) {
    __shared__ unsigned char lds[2][64][512];    // 2 x 32 KiB
    int strip = blockIdx.x >> 4;                 // 0..31  (256 rows)
    int slice = blockIdx.x & 15;                 // 0..15  (512 cols)
    int w     = threadIdx.x >> 6;                // 0..7
    int lane  = threadIdx.x & 63;
    int col   = lane & 15;
    int kg    = lane >> 4;                       // 0..3
    int c7    = col & 7;
    int r0    = strip * 256 + w * 32;
    int jb0   = slice * 512;

    // A fragments pinned: 2 m-tiles x 16 kk-steps, 8B each (64 VGPR)
    long afr[2][16];
    #pragma unroll
    for (int m = 0; m < 2; ++m) {
        const unsigned char* arow = Fb + (size_t)(r0 + m * 16 + col) * DIM;
        #pragma unroll
        for (int p = 0; p < 8; ++p) {
            uint4 qv = *(const uint4*)(arow + p * 64 + kg * 16);
            i64x2 v = __builtin_bit_cast(i64x2, qv);
            afr[m][2 * p]     = v.x;
            afr[m][2 * p + 1] = v.y;
        }
    }

    // stage 64-row x 512B tile; LDS linear, global source chunk-swizzled (chunk ^= row&7)
    auto stage = [&](int b, int t) {
        #pragma unroll
        for (int i = 0; i < 4; ++i) {
            int nb = i * 16 + w * 2;                 // wave-uniform base row (2 rows/issue)
            int n  = nb + (lane >> 5);
            int c  = lane & 31;
            const unsigned char* src =
                Fb + (size_t)(jb0 + t * 64 + n) * DIM + ((c ^ (n & 7)) << 4);
            __builtin_amdgcn_global_load_lds(AS1(src), AS3(&lds[b][nb][0]), 16, 0, 0);
        }
    };

    float S[2][4] = {{0.f,0.f,0.f,0.f},{0.f,0.f,0.f,0.f}};

    auto compute = [&](int b) {
        #pragma unroll
        for (int ct = 0; ct < 4; ++ct) {
            const unsigned char* rowbase = &lds[b][ct * 16 + col][0];
            f32x4 acc0 = {0.f,0.f,0.f,0.f}, acc1 = {0.f,0.f,0.f,0.f};
            #pragma unroll
            for (int p = 0; p < 8; ++p) {
                int off = ((((p << 2) + kg) ^ c7) << 4);
                uint4 qv = *(const uint4*)(rowbase + off);
                i64x2 v = __builtin_bit_cast(i64x2, qv);
                acc0 = __builtin_amdgcn_mfma_f32_16x16x32_fp8_fp8(afr[0][2*p],   v.x, acc0, 0, 0, 0);
                acc1 = __builtin_amdgcn_mfma_f32_16x16x32_fp8_fp8(afr[1][2*p],   v.x, acc1, 0, 0, 0);
                acc0 = __builtin_amdgcn_mfma_f32_16x16x32_fp8_fp8(afr[0][2*p+1], v.y, acc0, 0, 0, 0);
                acc1 = __builtin_amdgcn_mfma_f32_16x16x32_fp8_fp8(afr[1][2*p+1], v.y, acc1, 0, 0, 0);
            }
            #pragma unroll
            for (int r = 0; r < 4; ++r) {
                S[0][r] += exp2f(fmaf(acc0[r], K2C, -K2C));
                S[1][r] += exp2f(fmaf(acc1[r], K2C, -K2C));
            }
        }
    };

    stage(0, 0);
    for (int t = 0; t < NT; ++t) {
        __syncthreads();                       // staged tile t visible; prev reads drained
        if (t + 1 < NT) stage((t + 1) & 1, t + 1);
        compute(t & 1);
    }

    // sum across the 16 lanes holding the same output rows
    #pragma unroll
    for (int off = 1; off < 16; off <<= 1) {
        #pragma unroll
        for (int m = 0; m < 2; ++m)
            #pragma unroll
            for (int r = 0; r < 4; ++r)
                S[m][r] += __shfl_xor(S[m][r], off);
    }
    if (col == 0) {
        #pragma unroll
        for (int m = 0; m < 2; ++m)
            #pragma unroll
            for (int r = 0; r < 4; ++r)
                Sp[(size_t)slice * NROWS + r0 + m * 16 + kg * 4 + r] = S[m][r];
    }
}

// ---- 4. per-row loss term: one wave per row ----
__global__ void finalize_kernel(const unsigned char* __restrict__ Fb,
                                const int* __restrict__ labels,
                                const float* __restrict__ Sp,
                                const float* __restrict__ G,
                                const int* __restrict__ cnt,
                                float* __restrict__ rowvals) {
    int i    = blockIdx.x * 4 + (threadIdx.x >> 6);
    int lane = threadIdx.x & 63;
    int lab  = labels[i];
    uint2 rv8 = *(const uint2*)(Fb + (size_t)i * DIM + lane * 8);
    float f[8];
    f[0] = __builtin_amdgcn_cvt_f32_fp8((int)rv8.x, 0);
    f[1] = __builtin_amdgcn_cvt_f32_fp8((int)rv8.x, 1);
    f[2] = __builtin_amdgcn_cvt_f32_fp8((int)rv8.x, 2);
    f[3] = __builtin_amdgcn_cvt_f32_fp8((int)rv8.x, 3);
    f[4] = __builtin_amdgcn_cvt_f32_fp8((int)rv8.y, 0);
    f[5] = __builtin_amdgcn_cvt_f32_fp8((int)rv8.y, 1);
    f[6] = __builtin_amdgcn_cvt_f32_fp8((int)rv8.y, 2);
    f[7] = __builtin_amdgcn_cvt_f32_fp8((int)rv8.y, 3);
    const float4* g0p = (const float4*)(G + (size_t)lab * DIM);
    const float4* g1p = (const float4*)(G + (size_t)(NCLASS + lab) * DIM);
    float4 ga = g0p[2*lane], gb = g0p[2*lane+1];
    float4 gc = g1p[2*lane], gd = g1p[2*lane+1];
    float g[8] = {ga.x+gc.x, ga.y+gc.y, ga.z+gc.z, ga.w+gc.w,
                  gb.x+gd.x, gb.y+gd.y, gb.z+gd.z, gb.w+gd.w};
    float ss = 0.f, dot = 0.f;
    #pragma unroll
    for (int k = 0; k < 8; ++k) { ss = fmaf(f[k], f[k], ss); dot = fmaf(f[k], g[k], dot); }
    float sadd = (lane < NSLICE) ? Sp[(size_t)lane * NROWS + i] : 0.f;
    #pragma unroll
    for (int off = 32; off; off >>= 1) {
        ss   += __shfl_xor(ss, off);
        dot  += __shfl_xor(dot, off);
        sadd += __shfl_xor(sadd, off);
    }
    if (lane == 0) {
        float cntf  = (float)cnt[lab];
        float eself = exp2f(fmaf(ss, K2C, -K2C));   // matches MFMA diagonal (same fp8 values)
        float S     = sadd - eself + 1e-12f;
        rowvals[i]  = M0 + logf(S) - (dot * INV_TEMP) / cntf;
    }
}

// ---- 5. scalar reduce ----
__global__ void reduce_kernel(const float* __restrict__ rowvals, float* __restrict__ out) {
    float s = 0.f;
    for (int i = threadIdx.x; i < NROWS; i += 256) s += rowvals[i];
    #pragma unroll
    for (int off = 32; off; off >>= 1) s += __shfl_xor(s, off);
    __shared__ float buf[4];
    int w = threadIdx.x >> 6;
    if ((threadIdx.x & 63) == 0) buf[w] = s;
    __syncthreads();
    if (threadIdx.x == 0) out[0] = (buf[0] + buf[1] + buf[2] + buf[3]) * (1.0f / (float)NROWS);
}

extern "C" void kernel_launch(void* const* d_in, const int* in_sizes, int n_in,
                              void* d_out, int out_size, void* d_ws, size_t ws_size,
                              hipStream_t stream) {
    const float* F      = (const float*)d_in[0];
    const int*   labels = (const int*)d_in[1];
    float*       out    = (float*)d_out;
    char*        ws     = (char*)d_ws;

    unsigned char* Fb    = (unsigned char*)(ws + OFF_FB);
    float*         Sp    = (float*)(ws + OFF_SP);
    float*         G     = (float*)(ws + OFF_G);
    int*           lists = (int*)(ws + OFF_LIST);
    int*           icnt  = (int*)(ws + OFF_ICNT);
    float*         rv    = (float*)(ws + OFF_RV);

    hipMemsetAsync(icnt, 0, NCLASS * sizeof(int), stream);
    norm_kernel<<<NROWS / 4, 256, 0, stream>>>(F, labels, Fb, icnt, lists);
    classsum_kernel<<<NCLASS * NQ, 256, 0, stream>>>(Fb, icnt, lists, G);
    simstats_kernel<<<32 * NSLICE, 512, 0, stream>>>(Fb, Sp);
    finalize_kernel<<<NROWS / 4, 256, 0, stream>>>(Fb, labels, Sp, G, icnt, rv);
    reduce_kernel<<<1, 256, 0, stream>>>(rv, out);
}

// Round 5
// 97.239 us; speedup vs baseline: 4.5636x; 1.1165x over previous
//
#include <hip/hip_runtime.h>
#include <hip/hip_bf16.h>

#define NROWS 8192
#define DIM 512
#define NCLASS 100
#define NQ 2            // class-sum halves
#define NSLICE 16       // column slices of 512
#define NT 8            // 64-col tiles per slice
#define LISTCAP 1024
#define INV_TEMP 14.285714285714286f
#define M0 14.285714285714286f
#define K2C 20.609929155556663f   // (1/T)*log2(e)

typedef float f32x4 __attribute__((ext_vector_type(4)));
typedef int   i32x8 __attribute__((ext_vector_type(8)));

// ws layout (bytes)
#define OFF_FB   0u            // 8192*512*1  = 4194304 (fp8, fragment-paired layout)
#define OFF_SP   4194304u      // 16*8192*4   = 524288
#define OFF_G    4718592u      // 2*100*512*4 = 409600
#define OFF_LIST 5128192u      // 100*1024*4  = 409600
#define OFF_ICNT 5537792u      // 100*4
#define OFF_RV   5538192u      // 2048*4

#define AS1(p) ((const __attribute__((address_space(1))) void*)(p))
#define AS3(p) ((__attribute__((address_space(3))) void*)(p))

// Row byte layout (per 512-elem row): element e with kk=e>>5 (K32-step),
// kg=(e>>3)&3 (lane k-group), r=e&7 lives at byte (kk>>1)*64 + kg*16 + (kk&1)*8 + r.
// => 16B chunk p*64+kg*16 = (kk=2p,kg) frag || (kk=2p+1,kg) frag.
// => K128-block kb (kk=4kb..4kb+3) for lane kg = uint4 @ kb*128+kg*16 || uint4 @ kb*128+64+kg*16.
// Same permutation for every row => elementwise ops (class sums, dots) unaffected.

// ---- 1. L2-normalize rows -> fp8 (permuted layout); build per-class row lists ----
__global__ void norm_kernel(const float* __restrict__ F, const int* __restrict__ labels,
                            unsigned char* __restrict__ Fb,
                            int* __restrict__ cnt, int* __restrict__ lists) {
    int row  = blockIdx.x * 4 + (threadIdx.x >> 6);
    int lane = threadIdx.x & 63;
    const float4* src = (const float4*)(F + (size_t)row * DIM);
    float4 a = src[lane * 2];
    float4 b = src[lane * 2 + 1];
    float ss = a.x*a.x + a.y*a.y + a.z*a.z + a.w*a.w
             + b.x*b.x + b.y*b.y + b.z*b.z + b.w*b.w;
    #pragma unroll
    for (int off = 32; off; off >>= 1) ss += __shfl_xor(ss, off);
    float inv = 1.0f / sqrtf(ss);
    float f0 = a.x*inv, f1 = a.y*inv, f2 = a.z*inv, f3 = a.w*inv;
    float f4 = b.x*inv, f5 = b.y*inv, f6 = b.z*inv, f7 = b.w*inv;
    int w0 = __builtin_amdgcn_cvt_pk_fp8_f32(f0, f1, 0, false);
    w0     = __builtin_amdgcn_cvt_pk_fp8_f32(f2, f3, w0, true);
    int w1 = __builtin_amdgcn_cvt_pk_fp8_f32(f4, f5, 0, false);
    w1     = __builtin_amdgcn_cvt_pk_fp8_f32(f6, f7, w1, true);
    // lane holds elements e = lane*8..lane*8+7 -> (kk=lane>>2, kg=lane&3) frag
    int pofs = ((lane >> 3) << 6) + ((lane & 3) << 4) + (((lane >> 2) & 1) << 3);
    uint2 wv; wv.x = (unsigned)w0; wv.y = (unsigned)w1;
    *(uint2*)(Fb + (size_t)row * DIM + pofs) = wv;
    if (lane == 0) {
        int lab = labels[row];
        int pos = atomicAdd(&cnt[lab], 1);
        if (pos < LISTCAP) lists[lab * LISTCAP + pos] = row;
    }
}

// ---- 2. per-class feature sums via row lists (halved) ----
__global__ void classsum_kernel(const unsigned char* __restrict__ Fb,
                                const int* __restrict__ cnt,
                                const int* __restrict__ lists,
                                float* __restrict__ G) {
    int c = blockIdx.x % NCLASS;
    int q = blockIdx.x / NCLASS;
    int n = cnt[c];
    int lo = (n * q) / NQ, hi = (n * (q + 1)) / NQ;
    const int* lst = lists + c * LISTCAP;
    float g0 = 0.f, g1 = 0.f;
    #pragma unroll 4
    for (int p = lo; p < hi; ++p) {
        int r = lst[p];
        unsigned int u = *(const unsigned short*)(Fb + (size_t)r * DIM + threadIdx.x * 2);
        g0 += __builtin_amdgcn_cvt_f32_fp8(u, 0);
        g1 += __builtin_amdgcn_cvt_f32_fp8(u, 1);
    }
    float2* grow = (float2*)(G + ((size_t)q * NCLASS + c) * DIM);
    grow[threadIdx.x] = make_float2(g0, g1);
}

// ---- 3. MX-scaled FP8 MFMA (K=128, scales=1.0) similarity + exp-sum; M=64/wave ----
__global__ __launch_bounds__(256, 2)
void simstats_kernel(const unsigned char* __restrict__ Fb, float* __restrict__ Sp) {
    __shared__ unsigned char lds[2][64][512];    // 2 x 32 KiB
    int strip = blockIdx.x >> 4;                 // 0..31  (256 rows)
    int slice = blockIdx.x & 15;                 // 0..15  (512 cols)
    int w     = threadIdx.x >> 6;                // 0..3
    int lane  = threadIdx.x & 63;
    int col   = lane & 15;
    int kg    = lane >> 4;                       // 0..3
    int c7    = col & 7;
    int r0    = strip * 256 + w * 64;
    int jb0   = slice * 512;

    // A fragments pinned: 4 m-tiles x 4 K128-blocks x 32B (128 VGPR)
    i32x8 afr[4][4];
    #pragma unroll
    for (int m = 0; m < 4; ++m) {
        const unsigned char* arow = Fb + (size_t)(r0 + m * 16 + col) * DIM;
        #pragma unroll
        for (int kb = 0; kb < 4; ++kb) {
            uint4 lo = *(const uint4*)(arow + kb * 128 + kg * 16);
            uint4 hi = *(const uint4*)(arow + kb * 128 + 64 + kg * 16);
            i32x8 v;
            v[0] = (int)lo.x; v[1] = (int)lo.y; v[2] = (int)lo.z; v[3] = (int)lo.w;
            v[4] = (int)hi.x; v[5] = (int)hi.y; v[6] = (int)hi.z; v[7] = (int)hi.w;
            afr[m][kb] = v;
        }
    }

    // stage 64-row x 512B tile; LDS linear, global source chunk-swizzled (chunk ^= row&7)
    auto stage = [&](int b, int t) {
        #pragma unroll
        for (int i = 0; i < 8; ++i) {
            int nb = i * 8 + w * 2;                  // wave-uniform base row (2 rows/issue)
            int n  = nb + (lane >> 5);
            int c  = lane & 31;
            const unsigned char* src =
                Fb + (size_t)(jb0 + t * 64 + n) * DIM + ((c ^ (n & 7)) << 4);
            __builtin_amdgcn_global_load_lds(AS1(src), AS3(&lds[b][nb][0]), 16, 0, 0);
        }
    };

    float S[4][4] = {{0.f,0.f,0.f,0.f},{0.f,0.f,0.f,0.f},
                     {0.f,0.f,0.f,0.f},{0.f,0.f,0.f,0.f}};

    auto compute = [&](int b) {
        #pragma unroll
        for (int ct = 0; ct < 4; ++ct) {
            const unsigned char* rowbase = &lds[b][ct * 16 + col][0];
            i32x8 bop[4];
            #pragma unroll
            for (int kb = 0; kb < 4; ++kb) {
                uint4 lo = *(const uint4*)(rowbase + (((kb * 8 + kg)     ^ c7) << 4));
                uint4 hi = *(const uint4*)(rowbase + (((kb * 8 + 4 + kg) ^ c7) << 4));
                i32x8 v;
                v[0] = (int)lo.x; v[1] = (int)lo.y; v[2] = (int)lo.z; v[3] = (int)lo.w;
                v[4] = (int)hi.x; v[5] = (int)hi.y; v[6] = (int)hi.z; v[7] = (int)hi.w;
                bop[kb] = v;
            }
            f32x4 acc[4] = {{0.f,0.f,0.f,0.f},{0.f,0.f,0.f,0.f},
                            {0.f,0.f,0.f,0.f},{0.f,0.f,0.f,0.f}};
            #pragma unroll
            for (int m = 0; m < 4; ++m)
                #pragma unroll
                for (int kb = 0; kb < 4; ++kb)
                    acc[m] = __builtin_amdgcn_mfma_scale_f32_16x16x128_f8f6f4(
                        afr[m][kb], bop[kb], acc[m],
                        0, 0,                      // cbsz=fp8(e4m3), blgp=fp8(e4m3)
                        0, 0x7F7F7F7F,             // scaleA opsel, E8M0 1.0 (all bytes)
                        0, 0x7F7F7F7F);            // scaleB opsel, E8M0 1.0
            #pragma unroll
            for (int m = 0; m < 4; ++m)
                #pragma unroll
                for (int r = 0; r < 4; ++r)
                    S[m][r] += exp2f(fmaf(acc[m][r], K2C, -K2C));
        }
    };

    stage(0, 0);
    for (int t = 0; t < NT; ++t) {
        __syncthreads();                       // staged tile t visible; prev reads drained
        if (t + 1 < NT) stage((t + 1) & 1, t + 1);
        compute(t & 1);
    }

    // sum across the 16 lanes holding the same output rows
    #pragma unroll
    for (int off = 1; off < 16; off <<= 1) {
        #pragma unroll
        for (int m = 0; m < 4; ++m)
            #pragma unroll
            for (int r = 0; r < 4; ++r)
                S[m][r] += __shfl_xor(S[m][r], off);
    }
    if (col == 0) {
        #pragma unroll
        for (int m = 0; m < 4; ++m)
            #pragma unroll
            for (int r = 0; r < 4; ++r)
                Sp[(size_t)slice * NROWS + r0 + m * 16 + kg * 4 + r] = S[m][r];
    }
}

// ---- 4. per-row loss term: one wave per row; block partial sums ----
__global__ void finalize_kernel(const unsigned char* __restrict__ Fb,
                                const int* __restrict__ labels,
                                const float* __restrict__ Sp,
                                const float* __restrict__ G,
                                const int* __restrict__ cnt,
                                float* __restrict__ rv) {
    int i    = blockIdx.x * 4 + (threadIdx.x >> 6);
    int lane = threadIdx.x & 63;
    int lab  = labels[i];
    uint2 rv8 = *(const uint2*)(Fb + (size_t)i * DIM + lane * 8);
    float f[8];
    f[0] = __builtin_amdgcn_cvt_f32_fp8((int)rv8.x, 0);
    f[1] = __builtin_amdgcn_cvt_f32_fp8((int)rv8.x, 1);
    f[2] = __builtin_amdgcn_cvt_f32_fp8((int)rv8.x, 2);
    f[3] = __builtin_amdgcn_cvt_f32_fp8((int)rv8.x, 3);
    f[4] = __builtin_amdgcn_cvt_f32_fp8((int)rv8.y, 0);
    f[5] = __builtin_amdgcn_cvt_f32_fp8((int)rv8.y, 1);
    f[6] = __builtin_amdgcn_cvt_f32_fp8((int)rv8.y, 2);
    f[7] = __builtin_amdgcn_cvt_f32_fp8((int)rv8.y, 3);
    const float4* g0p = (const float4*)(G + (size_t)lab * DIM);
    const float4* g1p = (const float4*)(G + (size_t)(NCLASS + lab) * DIM);
    float4 ga = g0p[2*lane], gb = g0p[2*lane+1];
    float4 gc = g1p[2*lane], gd = g1p[2*lane+1];
    float g[8] = {ga.x+gc.x, ga.y+gc.y, ga.z+gc.z, ga.w+gc.w,
                  gb.x+gd.x, gb.y+gd.y, gb.z+gd.z, gb.w+gd.w};
    float ss = 0.f, dot = 0.f;
    #pragma unroll
    for (int k = 0; k < 8; ++k) { ss = fmaf(f[k], f[k], ss); dot = fmaf(f[k], g[k], dot); }
    float sadd = (lane < NSLICE) ? Sp[(size_t)lane * NROWS + i] : 0.f;
    #pragma unroll
    for (int off = 32; off; off >>= 1) {
        ss   += __shfl_xor(ss, off);
        dot  += __shfl_xor(dot, off);
        sadd += __shfl_xor(sadd, off);
    }
    __shared__ float pbuf[4];
    if (lane == 0) {
        float cntf  = (float)cnt[lab];
        float eself = exp2f(fmaf(ss, K2C, -K2C));   // matches MFMA diagonal (same fp8 values)
        float S     = sadd - eself + 1e-12f;
        pbuf[threadIdx.x >> 6] = M0 + logf(S) - (dot * INV_TEMP) / cntf;
    }
    __syncthreads();
    if (threadIdx.x == 0) rv[blockIdx.x] = pbuf[0] + pbuf[1] + pbuf[2] + pbuf[3];
}

// ---- 5. scalar reduce over 2048 block partials ----
__global__ void reduce_kernel(const float* __restrict__ rv, float* __restrict__ out) {
    float s = 0.f;
    #pragma unroll
    for (int i = threadIdx.x; i < NROWS / 4; i += 256) s += rv[i];
    #pragma unroll
    for (int off = 32; off; off >>= 1) s += __shfl_xor(s, off);
    __shared__ float buf[4];
    int w = threadIdx.x >> 6;
    if ((threadIdx.x & 63) == 0) buf[w] = s;
    __syncthreads();
    if (threadIdx.x == 0) out[0] = (buf[0] + buf[1] + buf[2] + buf[3]) * (1.0f / (float)NROWS);
}

extern "C" void kernel_launch(void* const* d_in, const int* in_sizes, int n_in,
                              void* d_out, int out_size, void* d_ws, size_t ws_size,
                              hipStream_t stream) {
    const float* F      = (const float*)d_in[0];
    const int*   labels = (const int*)d_in[1];
    float*       out    = (float*)d_out;
    char*        ws     = (char*)d_ws;

    unsigned char* Fb    = (unsigned char*)(ws + OFF_FB);
    float*         Sp    = (float*)(ws + OFF_SP);
    float*         G     = (float*)(ws + OFF_G);
    int*           lists = (int*)(ws + OFF_LIST);
    int*           icnt  = (int*)(ws + OFF_ICNT);
    float*         rv    = (float*)(ws + OFF_RV);

    hipMemsetAsync(icnt, 0, NCLASS * sizeof(int), stream);
    norm_kernel<<<NROWS / 4, 256, 0, stream>>>(F, labels, Fb, icnt, lists);
    classsum_kernel<<<NCLASS * NQ, 256, 0, stream>>>(Fb, icnt, lists, G);
    simstats_kernel<<<32 * NSLICE, 256, 0, stream>>>(Fb, Sp);
    finalize_kernel<<<NROWS / 4, 256, 0, stream>>>(Fb, labels, Sp, G, icnt, rv);
    reduce_kernel<<<1, 256, 0, stream>>>(rv, out);
}